// Round 6
// baseline (5709.920 us; speedup 1.0000x reference)
//
#include <hip/hip_runtime.h>

#define BATCH 512
#define NN    32
#define NVT   32
#define HS    501
#define VS    533
#define KP    512
#define NBLK  256
#define SLICE_BLOCKS 32

typedef short bf16x8 __attribute__((ext_vector_type(8)));
typedef float f32x4  __attribute__((ext_vector_type(4)));

__device__ __forceinline__ unsigned short f2bf(float f) {
    unsigned int u = __float_as_uint(f);
    u += 0x7fffu + ((u >> 16) & 1u);
    return (unsigned short)(u >> 16);
}
__device__ __forceinline__ float bf2f(unsigned short s) {
    return __uint_as_float(((unsigned int)s) << 16);
}
__device__ __forceinline__ float sigmoidf_(float x) { return 1.0f / (1.0f + __expf(-x)); }
__device__ __forceinline__ float tanhf_(float x)    { return 1.0f - 2.0f / (1.0f + __expf(2.0f * x)); }

#define N_WHH  (3 * KP * KP)
#define N_WGM  (2 * KP * KP)
#define N_GI   (3 * NVT * KP)
#define N_IDW  (2 * NN * KP)
#define N_WRT  (KP * NN)
#define N_MSGB (BATCH * KP)
#define N_ADJC (BATCH * NN)
#define N_TOT  (N_WHH + N_WGM + N_GI + N_IDW + N_WRT + N_MSGB + N_ADJC)

__global__ void prep_kernel(const float* __restrict__ W_hh, const float* __restrict__ Wg,
                            const float* __restrict__ Wm, const float* __restrict__ W_ih,
                            const float* __restrict__ b_ih, const float* __restrict__ b_hh,
                            const float* __restrict__ bg, const float* __restrict__ W_reg,
                            const float* __restrict__ adj,
                            unsigned short* __restrict__ Whh_p, unsigned short* __restrict__ Wgm_p,
                            float* __restrict__ gi_tab, float* __restrict__ idw,
                            float* __restrict__ WregT, unsigned short* __restrict__ MsgB,
                            unsigned int* __restrict__ adjcG)
{
    for (int i = blockIdx.x * blockDim.x + threadIdx.x; i < N_TOT; i += gridDim.x * blockDim.x) {
        int j = i;
        if (j < N_WHH) {
            int g = j >> 18, rem = j & (KP * KP - 1);
            int h = rem >> 9, k = rem & (KP - 1);
            float val = 0.0f;
            if (h < HS) {
                if (k < HS)        val = W_hh[(size_t)(g * HS + h) * HS + k];
                else if (k == HS)  val = b_hh[g * HS + h];   // bias folded at k=501
            }
            Whh_p[j] = f2bf(val);
            continue;
        }
        j -= N_WHH;
        if (j < N_WGM) {
            int m = j >> 18, rem = j & (KP * KP - 1);
            int h = rem >> 9, k = rem & (KP - 1);
            const float* src = m ? Wm : Wg;
            Wgm_p[j] = (h < HS && k < HS) ? f2bf(src[(size_t)h * VS + k]) : (unsigned short)0;
            continue;
        }
        j -= N_WGM;
        if (j < N_GI) {
            int g = j >> 14, typ = (j >> 9) & 31, h = j & (KP - 1);
            gi_tab[j] = (h < HS) ? (W_ih[(size_t)(g * HS + h) * NVT + typ] + b_ih[g * HS + h]) : 0.0f;
            continue;
        }
        j -= N_GI;
        if (j < N_IDW) {
            int m = j >> 14, v = (j >> 9) & 31, h = j & (KP - 1);
            float val = 0.0f;
            if (h < HS)
                val = m ? Wm[(size_t)h * VS + HS + v]
                        : (Wg[(size_t)h * VS + HS + v] + bg[h]);
            idw[j] = val;
            continue;
        }
        j -= N_IDW;
        if (j < N_WRT) {
            int k = j >> 5, ii = j & 31;
            WregT[j] = (k < HS) ? W_reg[(size_t)ii * HS + k] : 0.0f;
            continue;
        }
        j -= N_WRT;
        if (j < N_MSGB) {
            int k = j & (KP - 1);
            MsgB[j] = (k == HS) ? (unsigned short)0x3F80 : (unsigned short)0;  // bias col = 1.0
            continue;
        }
        j -= N_MSGB;
        {
            int b = j >> 5, vp = j & 31;
            unsigned int bits = 0;
            #pragma unroll
            for (int u = 0; u < 32; u++)
                bits |= (adj[((size_t)b * NN + u) * NN + vp] != 0.0f ? 1u : 0u) << u;
            adjcG[j] = bits;
        }
    }
}

// slice-local grid barrier: monotonic counter, 32 arrivals per phase
__device__ __forceinline__ void gsync(unsigned int* cnt, unsigned int target) {
    __syncthreads();
    __threadfence();                                   // release block's global writes
    if (threadIdx.x == 0) {
        __hip_atomic_fetch_add(cnt, 1u, __ATOMIC_RELEASE, __HIP_MEMORY_SCOPE_AGENT);
        while (__hip_atomic_load(cnt, __ATOMIC_ACQUIRE, __HIP_MEMORY_SCOPE_AGENT) < target)
            __builtin_amdgcn_s_sleep(8);
    }
    __syncthreads();
    __threadfence();                                   // acquire remote writes
}

// 256 blocks x 512 threads: block = (hblk = idx&31) x (bslc = idx>>5).
// Weights for its 16 h-cols live in LDS for the whole run.
__global__ __launch_bounds__(512, 2) void dvae_kernel(
    const unsigned short* __restrict__ Whh,   // [3*512][512] bf16 (k=501 = b_hh)
    const unsigned short* __restrict__ Wgm,   // [2*512][512] bf16
    const float* __restrict__ gi_tab,         // [3][32][512]
    const float* __restrict__ idw,            // [2][32][512]
    const int*   __restrict__ types,          // [512][32]
    const unsigned int* __restrict__ adjcG,   // [512][32] bitmask over u
    unsigned short* __restrict__ MsgB,        // [512][512] bf16 (+bias col 501)
    unsigned short* __restrict__ HvB,         // [512][512] bf16
    unsigned short* __restrict__ Ghist,       // [256 blk][32 u][64 b][16 h] bf16
    float* __restrict__ HvF,                  // [512][512] f32 (final step only)
    unsigned int* __restrict__ bar)           // [8][16] counters
{
    __shared__ unsigned short WLDS[80 * 512];     // 80 KB swizzled weights
    __shared__ float          Cred[12 * 256];     // 12 KB K-split reduce
    __shared__ float          MsgF_L[64 * 16];    // 4 KB f32 Msg mirror (own patch)
    __shared__ unsigned short GvL[64 * 16];       // 2 KB G_v staging
    __shared__ unsigned int   adjcL[64 * 32];     // 8 KB

    const int t    = threadIdx.x;
    const int hblk = blockIdx.x & 31, bslc = blockIdx.x >> 5;
    const int lane = t & 63, w = t >> 6;          // 8 waves
    const int c16  = lane & 15, kg = lane >> 4;
    const int bt   = w & 3, kh = w >> 2;          // wave task: btile x K-half
    unsigned int* cnt = bar + bslc * 16;

    // ---- stage weights into LDS, swizzled: row R in [0,80) = [Whh 48 | Wgm 32], k in [512)
    for (int i = 0; i < 10; i++) {
        const int seg = i * 512 + t;              // 16B segments, 5120 total
        const int R = seg >> 6, k8 = (seg & 63) * 8;
        const unsigned short* src;
        if (R < 48) {
            const int g = R >> 4, r = R & 15;
            src = Whh + (((size_t)(g * 512 + hblk * 16 + r)) << 9) + k8;
        } else {
            const int m = (R - 48) >> 4, r = (R - 48) & 15;
            src = Wgm + (((size_t)(m * 512 + hblk * 16 + r)) << 9) + k8;
        }
        const bf16x8 val = *(const bf16x8*)src;
        const int didx = ((R << 10) + (k8 << 1)) ^ ((R & 7) << 4);   // byte, swizzled
        *(bf16x8*)&WLDS[didx >> 1] = val;
    }
    for (int i = t; i < 64 * 32; i += 512) adjcL[i] = adjcG[bslc * (64 * 32) + i];
    for (int i = t; i < 64 * 16; i += 512) MsgF_L[i] = 0.0f;
    __syncthreads();

    unsigned short* Gblk = Ghist + (size_t)blockIdx.x * (32 * 64 * 16);
    unsigned int phase = 0;

    for (int v = 0; v < NN; v++) {
        // ======== phase A: gh = Msg @ Whh^T (3 gates, own 16 h-cols, own 64 rows) ========
        f32x4 a0 = {0.f,0.f,0.f,0.f}, a1 = a0, a2 = a0;
        {
            const unsigned short* aptr = MsgB + (((size_t)(bslc * 64 + bt * 16 + c16)) << 9)
                                              + kh * 256 + kg * 8;
            const int wi0 = (((c16 << 10) + ((kh * 256 + kg * 8) << 1)) ^ ((c16 & 7) << 4)) >> 1;
            const int wi1 = wi0 + 8192, wi2 = wi0 + 16384;
            #pragma unroll
            for (int kk = 0; kk < 8; kk++) {
                const bf16x8 af = *(const bf16x8*)(aptr + kk * 32);
                a0 = __builtin_amdgcn_mfma_f32_16x16x32_bf16(af, *(const bf16x8*)&WLDS[wi0 ^ (kk*32)], a0, 0, 0, 0);
                a1 = __builtin_amdgcn_mfma_f32_16x16x32_bf16(af, *(const bf16x8*)&WLDS[wi1 ^ (kk*32)], a1, 0, 0, 0);
                a2 = __builtin_amdgcn_mfma_f32_16x16x32_bf16(af, *(const bf16x8*)&WLDS[wi2 ^ (kk*32)], a2, 0, 0, 0);
            }
        }
        if (kh == 1) {
            #pragma unroll
            for (int j = 0; j < 4; j++) {
                const int pi = (kg * 4 + j) * 16 + c16;
                Cred[(bt * 3 + 0) * 256 + pi] = a0[j];
                Cred[(bt * 3 + 1) * 256 + pi] = a1[j];
                Cred[(bt * 3 + 2) * 256 + pi] = a2[j];
            }
        }
        __syncthreads();
        if (kh == 0) {
            const int h = hblk * 16 + c16;
            const bool ok = (h < HS);
            #pragma unroll
            for (int j = 0; j < 4; j++) {
                const int pi = (kg * 4 + j) * 16 + c16;
                const float s0 = a0[j] + Cred[(bt * 3 + 0) * 256 + pi];
                const float s1 = a1[j] + Cred[(bt * 3 + 1) * 256 + pi];
                const float s2 = a2[j] + Cred[(bt * 3 + 2) * 256 + pi];
                const int bl = bt * 16 + kg * 4 + j;
                const int bg_ = bslc * 64 + bl;
                float hv = 0.0f;
                if (ok) {
                    const int typ = types[bg_ * 32 + v];
                    const float gr = gi_tab[(0 * 32 + typ) * 512 + h];
                    const float gz = gi_tab[(1 * 32 + typ) * 512 + h];
                    const float gn = gi_tab[(2 * 32 + typ) * 512 + h];
                    const float hmsg = MsgF_L[bl * 16 + c16];
                    const float r = sigmoidf_(gr + s0);
                    const float z = sigmoidf_(gz + s1);
                    const float n = tanhf_(gn + r * s2);
                    hv = (1.0f - z) * n + z * hmsg;
                }
                HvB[((size_t)bg_ << 9) + h] = f2bf(hv);
                if (v == NN - 1) HvF[((size_t)bg_ << 9) + h] = hv;
            }
        }
        if (v == NN - 1) break;
        gsync(cnt, SLICE_BLOCKS * (++phase));

        // ======== phase B: z = Hv @ {Wg,Wm}^T ========
        f32x4 b0 = {0.f,0.f,0.f,0.f}, b1 = b0;
        {
            const unsigned short* aptr = HvB + (((size_t)(bslc * 64 + bt * 16 + c16)) << 9)
                                             + kh * 256 + kg * 8;
            const int wi0 = ((((48 + c16) << 10) + ((kh * 256 + kg * 8) << 1)) ^ ((c16 & 7) << 4)) >> 1;
            const int wi1 = wi0 + 8192;
            #pragma unroll
            for (int kk = 0; kk < 8; kk++) {
                const bf16x8 af = *(const bf16x8*)(aptr + kk * 32);
                b0 = __builtin_amdgcn_mfma_f32_16x16x32_bf16(af, *(const bf16x8*)&WLDS[wi0 ^ (kk*32)], b0, 0, 0, 0);
                b1 = __builtin_amdgcn_mfma_f32_16x16x32_bf16(af, *(const bf16x8*)&WLDS[wi1 ^ (kk*32)], b1, 0, 0, 0);
            }
        }
        if (kh == 1) {
            #pragma unroll
            for (int j = 0; j < 4; j++) {
                const int pi = (kg * 4 + j) * 16 + c16;
                Cred[(bt * 2 + 0) * 256 + pi] = b0[j];
                Cred[(bt * 2 + 1) * 256 + pi] = b1[j];
            }
        }
        __syncthreads();
        if (kh == 0) {
            const int h = hblk * 16 + c16;
            const bool ok = (h < HS);
            #pragma unroll
            for (int j = 0; j < 4; j++) {
                const int pi = (kg * 4 + j) * 16 + c16;
                const float s0 = b0[j] + Cred[(bt * 2 + 0) * 256 + pi];
                const float s1 = b1[j] + Cred[(bt * 2 + 1) * 256 + pi];
                const int bl = bt * 16 + kg * 4 + j;
                float gq = 0.0f;
                if (ok) {
                    const float zg = s0 + idw[(0 * 32 + v) * 512 + h];
                    const float zm = s1 + idw[(1 * 32 + v) * 512 + h];
                    gq = sigmoidf_(zg) * zm;
                }
                GvL[bl * 16 + c16] = f2bf(gq);
            }
        }
        __syncthreads();
        // ---- gather: persist G_v, assemble Msg_{v+1} for own (64 b x 16 h) patch
        if (t < 128) {
            const int bl = t >> 1, h8 = (t & 1) * 8;
            const bf16x8 g = *(const bf16x8*)&GvL[bl * 16 + h8];
            *(bf16x8*)&Gblk[((size_t)v * 64 + bl) * 16 + h8] = g;

            float msg[8] = {0.f,0.f,0.f,0.f,0.f,0.f,0.f,0.f};
            unsigned int mask = adjcL[bl * 32 + (v + 1)] & ((2u << v) - 1u);   // bits u <= v
            if ((mask >> v) & 1u) {
                #pragma unroll
                for (int x = 0; x < 8; x++) msg[x] += bf2f((unsigned short)g[x]);
                mask &= ~(1u << v);
            }
            while (mask) {
                const int u = __builtin_ctz(mask); mask &= mask - 1u;
                const bf16x8 a = *(const bf16x8*)&Gblk[((size_t)u * 64 + bl) * 16 + h8];
                #pragma unroll
                for (int x = 0; x < 8; x++) msg[x] += bf2f((unsigned short)a[x]);
            }
            const int hb_ = hblk * 16 + h8;
            if (hb_ <= HS && HS < hb_ + 8) msg[HS - hb_] = 1.0f;   // bias col k=501
            bf16x8 mb;
            #pragma unroll
            for (int x = 0; x < 8; x++) mb[x] = (short)f2bf(msg[x]);
            *(bf16x8*)&MsgB[(((size_t)(bslc * 64 + bl)) << 9) + hb_] = mb;
            #pragma unroll
            for (int x = 0; x < 8; x++) MsgF_L[bl * 16 + h8 + x] = msg[x];
        }
        gsync(cnt, SLICE_BLOCKS * (++phase));
    }
}

// mu = Hv31 @ W_reg^T + b_reg
__global__ __launch_bounds__(256) void final_kernel(
    const float* __restrict__ HvF,       // [512][512]
    const float* __restrict__ WregT,     // [512][32]
    const float* __restrict__ b_reg,     // [32]
    float* __restrict__ out)             // [512][32]
{
    const int t = blockIdx.x * 256 + threadIdx.x;
    const int b = t >> 5, i = t & 31;
    float s = b_reg[i];
    const float* hp = HvF + ((size_t)b << 9);
    #pragma unroll 4
    for (int k = 0; k < KP; k++) s += hp[k] * WregT[k * 32 + i];
    out[b * 32 + i] = s;
}

extern "C" void kernel_launch(void* const* d_in, const int* in_sizes, int n_in,
                              void* d_out, int out_size, void* d_ws, size_t ws_size,
                              hipStream_t stream) {
    const int*   node_types = (const int*)  d_in[0];
    const float* adj        = (const float*)d_in[1];
    const float* Wg         = (const float*)d_in[2];
    const float* bg         = (const float*)d_in[3];
    const float* Wm         = (const float*)d_in[4];
    const float* W_ih       = (const float*)d_in[5];
    const float* b_ih       = (const float*)d_in[6];
    const float* W_hh       = (const float*)d_in[7];
    const float* b_hh       = (const float*)d_in[8];
    const float* W_reg      = (const float*)d_in[9];
    const float* b_reg      = (const float*)d_in[10];
    float* out = (float*)d_out;

    char* p = (char*)d_ws;
    unsigned short* Whh_p = (unsigned short*)p; p += (size_t)N_WHH * 2;
    unsigned short* Wgm_p = (unsigned short*)p; p += (size_t)N_WGM * 2;
    float* gi_tab = (float*)p; p += (size_t)N_GI * 4;
    float* idw    = (float*)p; p += (size_t)N_IDW * 4;
    float* WregT  = (float*)p; p += (size_t)N_WRT * 4;
    float* HvF    = (float*)p; p += (size_t)BATCH * KP * 4;
    unsigned short* MsgB = (unsigned short*)p; p += (size_t)N_MSGB * 2;
    unsigned short* HvB  = (unsigned short*)p; p += (size_t)BATCH * KP * 2;
    unsigned int* adjcG  = (unsigned int*)p;  p += (size_t)N_ADJC * 4;
    unsigned int* bar    = (unsigned int*)p;  p += 8 * 16 * 4;
    unsigned short* Ghist = (unsigned short*)p; p += (size_t)NBLK * 32 * 64 * 16 * 2;

    hipMemsetAsync(bar, 0, 8 * 16 * 4, stream);
    prep_kernel<<<1024, 256, 0, stream>>>(W_hh, Wg, Wm, W_ih, b_ih, b_hh, bg, W_reg, adj,
                                          Whh_p, Wgm_p, gi_tab, idw, WregT, MsgB, adjcG);
    dvae_kernel<<<NBLK, 512, 0, stream>>>(Whh_p, Wgm_p, gi_tab, idw, node_types, adjcG,
                                          MsgB, HvB, Ghist, HvF, bar);
    final_kernel<<<(BATCH * NN) / 256, 256, 0, stream>>>(HvF, WregT, b_reg, out);
}

// Round 7
// 759.468 us; speedup vs baseline: 7.5183x; 7.5183x over previous
//
#include <hip/hip_runtime.h>

#define BATCH 512
#define NN    32
#define NVT   32
#define HS    501
#define VS    533
#define KP    512

typedef short bf16x8 __attribute__((ext_vector_type(8)));
typedef float f32x4  __attribute__((ext_vector_type(4)));

__device__ __forceinline__ unsigned short f2bf(float f) {
    unsigned int u = __float_as_uint(f);
    u += 0x7fffu + ((u >> 16) & 1u);
    return (unsigned short)(u >> 16);
}
__device__ __forceinline__ float bf2f(unsigned short s) {
    return __uint_as_float(((unsigned int)s) << 16);
}
__device__ __forceinline__ float sigmoidf_(float x) { return 1.0f / (1.0f + __expf(-x)); }
__device__ __forceinline__ float tanhf_(float x)    { return 1.0f - 2.0f / (1.0f + __expf(2.0f * x)); }

#define N_WHH  (3 * KP * KP)
#define N_WGM  (2 * KP * KP)
#define N_GI   (3 * NVT * KP)
#define N_IDW  (2 * NN * KP)
#define N_WRT  (KP * NN)
#define N_MSGB (BATCH * KP)
#define N_MSGF (BATCH * KP)
#define N_ADJC (BATCH * NN)
#define N_TOT  (N_WHH + N_WGM + N_GI + N_IDW + N_WRT + N_MSGB + N_MSGF + N_ADJC)

// One-time: bf16 weight repack (b_hh folded at k=501), gi table, id/bg table,
// WregT, Msg init (bf16 + f32), adjacency column bitmasks.
__global__ void prep_kernel(const float* __restrict__ W_hh, const float* __restrict__ Wg,
                            const float* __restrict__ Wm, const float* __restrict__ W_ih,
                            const float* __restrict__ b_ih, const float* __restrict__ b_hh,
                            const float* __restrict__ bg, const float* __restrict__ W_reg,
                            const float* __restrict__ adj,
                            unsigned short* __restrict__ Whh_p, unsigned short* __restrict__ Wgm_p,
                            float* __restrict__ gi_tab, float* __restrict__ idw,
                            float* __restrict__ WregT, unsigned short* __restrict__ MsgB,
                            float* __restrict__ MsgF, unsigned int* __restrict__ adjcG)
{
    for (int i = blockIdx.x * blockDim.x + threadIdx.x; i < N_TOT; i += gridDim.x * blockDim.x) {
        int j = i;
        if (j < N_WHH) {
            int g = j >> 18, rem = j & (KP * KP - 1);
            int h = rem >> 9, k = rem & (KP - 1);
            float val = 0.0f;
            if (h < HS) {
                if (k < HS)        val = W_hh[(size_t)(g * HS + h) * HS + k];
                else if (k == HS)  val = b_hh[g * HS + h];   // bias folded at k=501
            }
            Whh_p[j] = f2bf(val);
            continue;
        }
        j -= N_WHH;
        if (j < N_WGM) {
            int m = j >> 18, rem = j & (KP * KP - 1);
            int h = rem >> 9, k = rem & (KP - 1);
            const float* src = m ? Wm : Wg;
            Wgm_p[j] = (h < HS && k < HS) ? f2bf(src[(size_t)h * VS + k]) : (unsigned short)0;
            continue;
        }
        j -= N_WGM;
        if (j < N_GI) {
            int g = j >> 14, typ = (j >> 9) & 31, h = j & (KP - 1);
            gi_tab[j] = (h < HS) ? (W_ih[(size_t)(g * HS + h) * NVT + typ] + b_ih[g * HS + h]) : 0.0f;
            continue;
        }
        j -= N_GI;
        if (j < N_IDW) {
            int m = j >> 14, v = (j >> 9) & 31, h = j & (KP - 1);
            float val = 0.0f;
            if (h < HS)
                val = m ? Wm[(size_t)h * VS + HS + v]
                        : (Wg[(size_t)h * VS + HS + v] + bg[h]);
            idw[j] = val;
            continue;
        }
        j -= N_IDW;
        if (j < N_WRT) {
            int k = j >> 5, ii = j & 31;
            WregT[j] = (k < HS) ? W_reg[(size_t)ii * HS + k] : 0.0f;
            continue;
        }
        j -= N_WRT;
        if (j < N_MSGB) {
            int k = j & (KP - 1);
            MsgB[j] = (k == HS) ? (unsigned short)0x3F80 : (unsigned short)0;  // bias col = 1.0
            continue;
        }
        j -= N_MSGB;
        if (j < N_MSGF) { MsgF[j] = 0.0f; continue; }
        j -= N_MSGF;
        {
            int b = j >> 5, vp = j & 31;
            unsigned int bits = 0;
            #pragma unroll
            for (int u = 0; u < 32; u++)
                bits |= (adj[((size_t)b * NN + u) * NN + vp] != 0.0f ? 1u : 0u) << u;
            adjcG[j] = bits;
        }
    }
}

// Step A: gh = Msg @ Whh^T (3 gates) + GRU epilogue -> HvB (bf16) [+ HvF at v=31].
// grid (32, 8), block 256 (4 waves); wave = 16b x 16h, full K=512, no LDS, no barriers.
__global__ __launch_bounds__(256) void gru_kernel(
    const unsigned short* __restrict__ MsgB,  // [512][512] bf16 (bias col 501 = 1)
    const float* __restrict__ MsgF,           // [512][512] f32
    const unsigned short* __restrict__ Whh,   // [3*512][512] bf16
    const float* __restrict__ gi_tab,         // [3][32][512]
    const int* __restrict__ types,            // [512][32]
    unsigned short* __restrict__ HvB,         // [512][512] bf16
    float* __restrict__ HvF,                  // [512][512] f32 (last step)
    int v)
{
    const int t = threadIdx.x;
    const int lane = t & 63, w = t >> 6;
    const int c16 = lane & 15, kg = lane >> 4;
    const int bb = blockIdx.x * 16;
    const int hw = blockIdx.y * 64 + w * 16;

    const unsigned short* Ar = MsgB + (((size_t)(bb + c16)) << 9) + kg * 8;
    const unsigned short* w0 = Whh + (((size_t)(0 * KP + hw + c16)) << 9) + kg * 8;
    const unsigned short* w1 = Whh + (((size_t)(1 * KP + hw + c16)) << 9) + kg * 8;
    const unsigned short* w2 = Whh + (((size_t)(2 * KP + hw + c16)) << 9) + kg * 8;

    f32x4 a0 = {0.f,0.f,0.f,0.f}, a1 = a0, a2 = a0;
    #pragma unroll
    for (int kk = 0; kk < 16; kk++) {
        const bf16x8 af = *(const bf16x8*)(Ar + kk * 32);
        a0 = __builtin_amdgcn_mfma_f32_16x16x32_bf16(af, *(const bf16x8*)(w0 + kk * 32), a0, 0, 0, 0);
        a1 = __builtin_amdgcn_mfma_f32_16x16x32_bf16(af, *(const bf16x8*)(w1 + kk * 32), a1, 0, 0, 0);
        a2 = __builtin_amdgcn_mfma_f32_16x16x32_bf16(af, *(const bf16x8*)(w2 + kk * 32), a2, 0, 0, 0);
    }

    const int h = hw + c16;
    const bool ok = (h < HS);
    const bool last = (v == NN - 1);
    #pragma unroll
    for (int j = 0; j < 4; j++) {
        const int b = bb + kg * 4 + j;
        float hv = 0.0f;
        if (ok) {
            const int typ = types[b * NN + v];
            const float gr = gi_tab[(0 * NVT + typ) * KP + h];
            const float gz = gi_tab[(1 * NVT + typ) * KP + h];
            const float gn = gi_tab[(2 * NVT + typ) * KP + h];
            const float hmsg = MsgF[((size_t)b << 9) + h];
            const float r = sigmoidf_(gr + a0[j]);
            const float z = sigmoidf_(gz + a1[j]);
            const float n = tanhf_(gn + r * a2[j]);
            hv = (1.0f - z) * n + z * hmsg;
        }
        HvB[((size_t)b << 9) + h] = f2bf(hv);
        if (last) HvF[((size_t)b << 9) + h] = hv;
    }
}

// Step B: z = Hv @ {Wg,Wm}^T ; G_v = sigmoid(zg+id+bg)*(zm+id) -> Gbuf;
// gather Msg_{v+1}[b,h] = sum_{u<=v} edge(u,v+1) * G_u[b,h]  (+bias col).
// grid (32, 8), block 256; wave = 16b x 16h, full K, no LDS, no barriers.
__global__ __launch_bounds__(256) void gate_kernel(
    const unsigned short* __restrict__ HvB,   // [512][512] bf16
    const unsigned short* __restrict__ Wgm,   // [2*512][512] bf16
    const float* __restrict__ idw,            // [2][32][512]
    const unsigned int* __restrict__ adjcG,   // [512][32] bitmask over u
    unsigned short* __restrict__ Gbuf,        // [32][512][512] bf16
    unsigned short* __restrict__ MsgB,        // [512][512] bf16
    float* __restrict__ MsgF,                 // [512][512] f32
    int v)
{
    const int t = threadIdx.x;
    const int lane = t & 63, w = t >> 6;
    const int c16 = lane & 15, kg = lane >> 4;
    const int bb = blockIdx.x * 16;
    const int hw = blockIdx.y * 64 + w * 16;

    const unsigned short* Ar = HvB + (((size_t)(bb + c16)) << 9) + kg * 8;
    const unsigned short* w0 = Wgm + (((size_t)(0 * KP + hw + c16)) << 9) + kg * 8;
    const unsigned short* w1 = Wgm + (((size_t)(1 * KP + hw + c16)) << 9) + kg * 8;

    f32x4 b0 = {0.f,0.f,0.f,0.f}, b1 = b0;
    #pragma unroll
    for (int kk = 0; kk < 16; kk++) {
        const bf16x8 af = *(const bf16x8*)(Ar + kk * 32);
        b0 = __builtin_amdgcn_mfma_f32_16x16x32_bf16(af, *(const bf16x8*)(w0 + kk * 32), b0, 0, 0, 0);
        b1 = __builtin_amdgcn_mfma_f32_16x16x32_bf16(af, *(const bf16x8*)(w1 + kk * 32), b1, 0, 0, 0);
    }

    const int h = hw + c16;
    const bool ok = (h < HS);
    const float id0 = ok ? idw[(0 * NN + v) * KP + h] : 0.0f;
    const float id1 = ok ? idw[(1 * NN + v) * KP + h] : 0.0f;

    #pragma unroll
    for (int j = 0; j < 4; j++) {
        const int b = bb + kg * 4 + j;
        float gq = 0.0f;
        if (ok) gq = sigmoidf_(b0[j] + id0) * (b1[j] + id1);
        const unsigned short gbits = f2bf(gq);
        Gbuf[(((size_t)v << 9) + b) * KP + h] = gbits;

        float msg = 0.0f;
        unsigned int mask = adjcG[b * NN + (v + 1)];     // bits u <= v only (triu)
        if ((mask >> v) & 1u) { msg += bf2f(gbits); mask &= ~(1u << v); }
        while (mask) {
            const int u = __builtin_ctz(mask); mask &= mask - 1u;
            msg += bf2f(Gbuf[(((size_t)u << 9) + b) * KP + h]);
        }
        if (h == HS) msg = 1.0f;                          // bias column
        MsgB[((size_t)b << 9) + h] = f2bf(msg);
        MsgF[((size_t)b << 9) + h] = msg;
    }
}

// mu = Hv31 @ W_reg^T + b_reg
__global__ __launch_bounds__(256) void final_kernel(
    const float* __restrict__ HvF,       // [512][512]
    const float* __restrict__ WregT,     // [512][32]
    const float* __restrict__ b_reg,     // [32]
    float* __restrict__ out)             // [512][32]
{
    const int t = blockIdx.x * 256 + threadIdx.x;
    const int b = t >> 5, i = t & 31;
    float s = b_reg[i];
    const float* hp = HvF + ((size_t)b << 9);
    #pragma unroll 4
    for (int k = 0; k < KP; k++) s += hp[k] * WregT[k * 32 + i];
    out[b * 32 + i] = s;
}

extern "C" void kernel_launch(void* const* d_in, const int* in_sizes, int n_in,
                              void* d_out, int out_size, void* d_ws, size_t ws_size,
                              hipStream_t stream) {
    const int*   node_types = (const int*)  d_in[0];
    const float* adj        = (const float*)d_in[1];
    const float* Wg         = (const float*)d_in[2];
    const float* bg         = (const float*)d_in[3];
    const float* Wm         = (const float*)d_in[4];
    const float* W_ih       = (const float*)d_in[5];
    const float* b_ih       = (const float*)d_in[6];
    const float* W_hh       = (const float*)d_in[7];
    const float* b_hh       = (const float*)d_in[8];
    const float* W_reg      = (const float*)d_in[9];
    const float* b_reg      = (const float*)d_in[10];
    float* out = (float*)d_out;

    char* p = (char*)d_ws;
    unsigned short* Whh_p = (unsigned short*)p; p += (size_t)N_WHH * 2;
    unsigned short* Wgm_p = (unsigned short*)p; p += (size_t)N_WGM * 2;
    float* gi_tab = (float*)p; p += (size_t)N_GI * 4;
    float* idw    = (float*)p; p += (size_t)N_IDW * 4;
    float* WregT  = (float*)p; p += (size_t)N_WRT * 4;
    unsigned short* MsgB = (unsigned short*)p; p += (size_t)N_MSGB * 2;
    float* MsgF   = (float*)p; p += (size_t)N_MSGF * 4;
    unsigned short* HvB  = (unsigned short*)p; p += (size_t)BATCH * KP * 2;
    float* HvF    = (float*)p; p += (size_t)BATCH * KP * 4;
    unsigned int* adjcG  = (unsigned int*)p;  p += (size_t)N_ADJC * 4;
    unsigned short* Gbuf = (unsigned short*)p; p += (size_t)NN * BATCH * KP * 2;

    prep_kernel<<<2048, 256, 0, stream>>>(W_hh, Wg, Wm, W_ih, b_ih, b_hh, bg, W_reg, adj,
                                          Whh_p, Wgm_p, gi_tab, idw, WregT, MsgB, MsgF, adjcG);

    dim3 grd(BATCH / 16, KP / 64);   // 32 x 8 = 256 blocks
    for (int v = 0; v < NN; v++) {
        gru_kernel<<<grd, 256, 0, stream>>>(MsgB, MsgF, Whh_p, gi_tab, node_types, HvB, HvF, v);
        if (v < NN - 1)
            gate_kernel<<<grd, 256, 0, stream>>>(HvB, Wgm_p, idw, adjcG, Gbuf, MsgB, MsgF, v);
    }
    final_kernel<<<(BATCH * NN) / 256, 256, 0, stream>>>(HvF, WregT, b_reg, out);
}